// Round 13
// baseline (158.136 us; speedup 1.0000x reference)
//
#include <hip/hip_runtime.h>

// LAYER_IDX = [0, 4096, 6144, 7168, 7680, 7682]
// layer1: 4096->2048 ebase 0       | layer2: 2048->1024 ebase 262144
// layer3: 1024->512  ebase 393216  | out: 512->2        ebase 458752
#define BATCH 512
#define FAN_IN 128
#define EPS 1e-5f

typedef unsigned short u16;
typedef unsigned int u32;
typedef __attribute__((ext_vector_type(8))) short short8;   // 8 bf16
typedef __attribute__((ext_vector_type(4))) float f32x4;

__device__ __forceinline__ u16 f2bf(float f) {   // fp32->bf16 RNE
    union { float f; u32 u; } v; v.f = f;
    u32 r = v.u + 0x7fffu + ((v.u >> 16) & 1u);
    return (u16)(r >> 16);
}
__device__ __forceinline__ float bf2f(u16 h) {
    union { u32 u; float f; } v; v.u = ((u32)h) << 16; return v.f;
}
__device__ __forceinline__ void ld16(const void* g, void* l) {  // async global->LDS 16B
    __builtin_amdgcn_global_load_lds(
        (const __attribute__((address_space(1))) u32*)g,
        (__attribute__((address_space(3))) u32*)l, 16, 0, 0);
}

// ---------------------------------------------------------------------------
// Densify one target node's sparse weights into a dense bf16 row (LDS scratch).
__device__ __forceinline__ void densify_node(
    float* row, int Kin, int ebase, int srcbase, u16* outrow,
    const float* __restrict__ weight, const int* __restrict__ edge_src) {
    const int t = threadIdx.x;
    for (int k = t; k < Kin; k += 256) row[k] = 0.f;
    __syncthreads();
    if (t < FAN_IN)
        atomicAdd(&row[edge_src[ebase + t] - srcbase], weight[ebase + t]);
    __syncthreads();
    for (int k0 = t * 8; k0 < Kin; k0 += 2048) {
        u16 pk[8];
#pragma unroll
        for (int i = 0; i < 8; ++i) pk[i] = f2bf(row[k0 + i]);
        *(uint4*)(outrow + k0) = *(const uint4*)pk;
    }
}

// ---------------------------------------------------------------------------
// prep: densify W1 (bf16 [m][k]) + convert x -> bf16 batch-major. 2560 blocks.
__global__ __launch_bounds__(256) void prep(
    const float* __restrict__ weight, const int* __restrict__ edge_src,
    const float* __restrict__ x, u16* __restrict__ Wd, u16* __restrict__ xb) {
    __shared__ float row[4096];
    const int bid = blockIdx.x, t = threadIdx.x;
    if (bid < 2048) {
        densify_node(row, 4096, bid * 128, 0, Wd + (size_t)bid * 4096,
                     weight, edge_src);
    } else {
        const int b = bid - 2048;
        const float* xr = x + (size_t)b * 4096;
        u16* xo = xb + (size_t)b * 4096;
        for (int k0 = t * 8; k0 < 4096; k0 += 2048) {
            const float4 f0 = *(const float4*)(xr + k0);
            const float4 f1 = *(const float4*)(xr + k0 + 4);
            uint4 pk;
            pk.x = f2bf(f0.x) | ((u32)f2bf(f0.y) << 16);
            pk.y = f2bf(f0.z) | ((u32)f2bf(f0.w) << 16);
            pk.z = f2bf(f1.x) | ((u32)f2bf(f1.y) << 16);
            pk.w = f2bf(f1.z) | ((u32)f2bf(f1.w) << 16);
            *(uint4*)(xo + k0) = pk;
        }
    }
}

// ---------------------------------------------------------------------------
// Proven partial-GEMM body (R12): Cz[z][n=batch][m=node] over K-chunk z.
// 64x64 tile, BK=32, dbuf LDS via global_load_lds, XOR swizzle, plain stores.
__device__ __forceinline__ void gemm_body(
    u16* SM, int m_t, int n_t, int z, const u16* __restrict__ Act,
    const u16* __restrict__ W, float* __restrict__ Cz, int M, int K,
    int kchunk) {
    u16* sA = SM;            // 2 x 2048 u16
    u16* sB = SM + 4096;
    const int tid = threadIdx.x;
    const int m0 = m_t * 64, n0 = n_t * 64, kbase = z * kchunk;
    float* Cp = Cz + (size_t)z * BATCH * M;

    const int r = tid >> 2, c = tid & 3;
    const int q = c ^ ((r ^ (r >> 2)) & 3);
    const u16* gA = Act + (size_t)(n0 + r) * K + kbase + q * 8;
    const u16* gB = W + (size_t)(m0 + r) * K + kbase + q * 8;
    const int lo = tid * 8;

    const int wave = tid >> 6, lane = tid & 63;
    const int l15 = lane & 15, quad = lane >> 4;
    const int aoff = (wave & 1) * 32, boff = (wave >> 1) * 32;
    int offA[2], offB[2];
#pragma unroll
    for (int i = 0; i < 2; ++i) {
        const int ra = aoff + i * 16 + l15;
        offA[i] = ra * 32 + ((quad ^ ((ra ^ (ra >> 2)) & 3)) * 8);
        const int rb = boff + i * 16 + l15;
        offB[i] = rb * 32 + ((quad ^ ((rb ^ (rb >> 2)) & 3)) * 8);
    }

    f32x4 acc[2][2] = {};
    const int niter = kchunk >> 5;
    ld16(gA, &sA[lo]); ld16(gB, &sB[lo]);
    for (int it = 0; it < niter; ++it) {
        __syncthreads();
        if (it + 1 < niter) {
            const int k0 = (it + 1) << 5;
            const int nb = ((it + 1) & 1) * 2048;
            ld16(gA + k0, &sA[nb + lo]); ld16(gB + k0, &sB[nb + lo]);
        }
        const u16* a = sA + (it & 1) * 2048;
        const u16* b = sB + (it & 1) * 2048;
        const short8 a0 = *(const short8*)(a + offA[0]);
        const short8 a1 = *(const short8*)(a + offA[1]);
        const short8 b0 = *(const short8*)(b + offB[0]);
        const short8 b1 = *(const short8*)(b + offB[1]);
        acc[0][0] = __builtin_amdgcn_mfma_f32_16x16x32_bf16(a0, b0, acc[0][0], 0, 0, 0);
        acc[0][1] = __builtin_amdgcn_mfma_f32_16x16x32_bf16(a0, b1, acc[0][1], 0, 0, 0);
        acc[1][0] = __builtin_amdgcn_mfma_f32_16x16x32_bf16(a1, b0, acc[1][0], 0, 0, 0);
        acc[1][1] = __builtin_amdgcn_mfma_f32_16x16x32_bf16(a1, b1, acc[1][1], 0, 0, 0);
    }
#pragma unroll
    for (int i = 0; i < 2; ++i) {
        const int nb = n_t * 64 + aoff + i * 16 + quad * 4;
#pragma unroll
        for (int rr = 0; rr < 4; ++rr)
#pragma unroll
            for (int j = 0; j < 2; ++j) {
                const int mg = m0 + boff + j * 16 + l15;
                Cp[(size_t)(nb + rr) * M + mg] = acc[i][j][rr];
            }
    }
}

// ---------------------------------------------------------------------------
// G1 + W2/W3 densify fused: 1D grid, 2560 blocks.
//  bid < 1024          : G1 gemm unit (m fastest: 32m x 8n x 4z, kchunk 1024)
//  1024 <= bid < 2048  : densify W2 node (Kin 2048)
//  2048 <= bid < 2560  : densify W3 node (Kin 1024)
__global__ __launch_bounds__(256, 8) void g1d(
    const u16* __restrict__ xb, u16* __restrict__ Wd, float* __restrict__ Cz1,
    const float* __restrict__ weight, const int* __restrict__ edge_src) {
    __shared__ u16 SM[8192];   // 16 KB (gemm staging / densify row alias)
    const int bid = blockIdx.x;
    if (bid < 1024) {
        gemm_body(SM, bid & 31, (bid >> 5) & 7, bid >> 8, xb, Wd, Cz1,
                  2048, 4096, 1024);
    } else if (bid < 2048) {
        const int u = bid - 1024;
        densify_node((float*)SM, 2048, 262144 + u * 128, 4096,
                     Wd + 8388608 + (size_t)u * 2048, weight, edge_src);
    } else {
        const int u = bid - 2048;
        densify_node((float*)SM, 1024, 393216 + u * 128, 6144,
                     Wd + 10485760 + (size_t)u * 1024, weight, edge_src);
    }
}

// ---------------------------------------------------------------------------
// G2 standalone (proven 3D form): grid (M/64, 8, Z).
__global__ __launch_bounds__(256, 8) void gemm_bt(
    const u16* __restrict__ Act, const u16* __restrict__ W,
    float* __restrict__ Cz, int M, int K, int kchunk) {
    __shared__ u16 SM[8192];
    gemm_body(SM, blockIdx.x, blockIdx.y, blockIdx.z, Act, W, Cz, M, K, kchunk);
}

// ---------------------------------------------------------------------------
// fin1: one block per batch row n. Sum Z partials + bias into LDS, row
// mean/var, LN+ReLU from LDS, write bf16 actb[n][m]. (R12-proven.)
template <int M, int Z>
__global__ __launch_bounds__(256) void fin(
    const float* __restrict__ Cz, const float* __restrict__ bias_l,
    const float* __restrict__ gamma_l, const float* __restrict__ beta_l,
    u16* __restrict__ actb) {
    __shared__ float rowL[M];
    __shared__ float red[8];
    __shared__ float mrs[2];
    const int n = blockIdx.x, t = threadIdx.x;
    const size_t zs = (size_t)BATCH * M;
    const float* base = Cz + (size_t)n * M;

    float sum = 0.f, sq = 0.f;
    for (int m = t * 4; m < M; m += 1024) {
        float4 v = *(const float4*)(bias_l + m);
#pragma unroll
        for (int z = 0; z < Z; ++z) {
            const float4 cv = *(const float4*)(base + (size_t)z * zs + m);
            v.x += cv.x; v.y += cv.y; v.z += cv.z; v.w += cv.w;
        }
        *(float4*)(rowL + m) = v;
        sum += v.x + v.y + v.z + v.w;
        sq += v.x * v.x + v.y * v.y + v.z * v.z + v.w * v.w;
    }
#pragma unroll
    for (int o = 32; o; o >>= 1) { sum += __shfl_down(sum, o); sq += __shfl_down(sq, o); }
    if ((t & 63) == 0) { red[(t >> 6) * 2] = sum; red[(t >> 6) * 2 + 1] = sq; }
    __syncthreads();
    if (t == 0) {
        const float s = red[0] + red[2] + red[4] + red[6];
        const float qq = red[1] + red[3] + red[5] + red[7];
        const float mean = s / (float)M;
        const float var = qq / (float)M - mean * mean;
        mrs[0] = mean; mrs[1] = rsqrtf(var + EPS);
    }
    __syncthreads();
    const float mean = mrs[0], rstd = mrs[1];
    for (int m = t * 4; m < M; m += 1024) {
        const float4 v = *(const float4*)(rowL + m);
        const float4 g = *(const float4*)(gamma_l + m);
        const float4 bt = *(const float4*)(beta_l + m);
        u16 pk[4] = {
            f2bf(fmaxf(fmaf(g.x * (v.x - mean), rstd, bt.x), 0.f)),
            f2bf(fmaxf(fmaf(g.y * (v.y - mean), rstd, bt.y), 0.f)),
            f2bf(fmaxf(fmaf(g.z * (v.z - mean), rstd, bt.z), 0.f)),
            f2bf(fmaxf(fmaf(g.w * (v.w - mean), rstd, bt.w), 0.f))};
        *(uint2*)(actb + (size_t)n * M + m) = *(const uint2*)pk;
    }
}

// ---------------------------------------------------------------------------
// finL: layer-2 finish + layer-3 GEMV + LN3 + output, 4 batch rows per block.
// Phase A: sum Z=4 Cz2 partials + bias -> LN2+ReLU -> rowL[4][1024] (f32 LDS).
// Phase B: y[i][j] = W3[j][:] . rowL[i][:], register-blocked (acc[16][4]),
//          W3 (1 MB bf16) is L2-resident and reused 4x per load.
// Phase C: per-row LN3 + ReLU in LDS, then 2-node sparse output layer.
__global__ __launch_bounds__(256) void finL(
    const float* __restrict__ Cz2, const float* __restrict__ bias2,
    const float* __restrict__ g2, const float* __restrict__ b2,
    const u16* __restrict__ W3, const float* __restrict__ bias3,
    const float* __restrict__ g3, const float* __restrict__ b3,
    const float* __restrict__ weight, const int* __restrict__ edge_src,
    const float* __restrict__ obias, float* __restrict__ out) {
    __shared__ float rowL[4][1024];   // 16 KB
    __shared__ float yL[4][512];      // 8 KB
    __shared__ float red[8];
    __shared__ float mrs[2];
    __shared__ float w_s[256];
    __shared__ int   s_s[256];
    __shared__ float pr[256];

    const int t = threadIdx.x;
    const int n0 = blockIdx.x * 4;
    const int wv = t >> 6, ln = t & 63;
    w_s[t] = weight[458752 + t];
    s_s[t] = edge_src[458752 + t] - 7168;

    // ---- Phase A: layer-2 finish (4 rows; 256 thr x float4 covers M=1024)
    for (int i = 0; i < 4; ++i) {
        const float* base = Cz2 + (size_t)(n0 + i) * 1024 + t * 4;
        float4 v = *(const float4*)(bias2 + t * 4);
#pragma unroll
        for (int z = 0; z < 4; ++z) {
            const float4 cv = *(const float4*)(base + (size_t)z * (512 * 1024));
            v.x += cv.x; v.y += cv.y; v.z += cv.z; v.w += cv.w;
        }
        float sum = v.x + v.y + v.z + v.w;
        float sq = v.x * v.x + v.y * v.y + v.z * v.z + v.w * v.w;
#pragma unroll
        for (int o = 32; o; o >>= 1) { sum += __shfl_down(sum, o); sq += __shfl_down(sq, o); }
        if (ln == 0) { red[wv * 2] = sum; red[wv * 2 + 1] = sq; }
        __syncthreads();
        if (t == 0) {
            const float s = red[0] + red[2] + red[4] + red[6];
            const float qq = red[1] + red[3] + red[5] + red[7];
            const float mean = s * (1.f / 1024.f);
            const float var = qq * (1.f / 1024.f) - mean * mean;
            mrs[0] = mean; mrs[1] = rsqrtf(var + EPS);
        }
        __syncthreads();
        const float mean = mrs[0], rstd = mrs[1];
        const float4 g = *(const float4*)(g2 + t * 4);
        const float4 bb = *(const float4*)(b2 + t * 4);
        rowL[i][t * 4 + 0] = fmaxf(fmaf(g.x * (v.x - mean), rstd, bb.x), 0.f);
        rowL[i][t * 4 + 1] = fmaxf(fmaf(g.y * (v.y - mean), rstd, bb.y), 0.f);
        rowL[i][t * 4 + 2] = fmaxf(fmaf(g.z * (v.z - mean), rstd, bb.z), 0.f);
        rowL[i][t * 4 + 3] = fmaxf(fmaf(g.w * (v.w - mean), rstd, bb.w), 0.f);
        __syncthreads();
    }

    // ---- Phase B: layer-3 GEMV (512 nodes x 4 rows)
    const int jrow = t >> 3;          // 0..31 (node within group)
    const int ko = (t & 7) * 8;       // k offset within 64-chunk
    float acc[16][4];
#pragma unroll
    for (int jg = 0; jg < 16; ++jg)
#pragma unroll
        for (int i = 0; i < 4; ++i) acc[jg][i] = 0.f;

    for (int k0 = 0; k0 < 1024; k0 += 64) {
        float rv[4][8];
#pragma unroll
        for (int i = 0; i < 4; ++i) {
            const float4 r0 = *(const float4*)(&rowL[i][k0 + ko]);
            const float4 r1 = *(const float4*)(&rowL[i][k0 + ko + 4]);
            rv[i][0] = r0.x; rv[i][1] = r0.y; rv[i][2] = r0.z; rv[i][3] = r0.w;
            rv[i][4] = r1.x; rv[i][5] = r1.y; rv[i][6] = r1.z; rv[i][7] = r1.w;
        }
#pragma unroll
        for (int jg = 0; jg < 16; ++jg) {
            const uint4 pk = *(const uint4*)(W3 + (size_t)(jg * 32 + jrow) * 1024 + k0 + ko);
            const u16* pw = (const u16*)&pk;
#pragma unroll
            for (int e = 0; e < 8; ++e) {
                const float w = bf2f(pw[e]);
                acc[jg][0] += w * rv[0][e];
                acc[jg][1] += w * rv[1][e];
                acc[jg][2] += w * rv[2][e];
                acc[jg][3] += w * rv[3][e];
            }
        }
    }
#pragma unroll
    for (int jg = 0; jg < 16; ++jg) {
        const int j = jg * 32 + jrow;
#pragma unroll
        for (int i = 0; i < 4; ++i) {
            float a = acc[jg][i];
            a += __shfl_xor(a, 1); a += __shfl_xor(a, 2); a += __shfl_xor(a, 4);
            if ((t & 7) == 0) yL[i][j] = a + bias3[j];
        }
    }
    __syncthreads();

    // ---- Phase C: LN3 + ReLU + 2-node output, per row
    for (int i = 0; i < 4; ++i) {
        const float v0 = yL[i][t], v1 = yL[i][t + 256];
        float sum = v0 + v1, sq = v0 * v0 + v1 * v1;
#pragma unroll
        for (int o = 32; o; o >>= 1) { sum += __shfl_down(sum, o); sq += __shfl_down(sq, o); }
        if (ln == 0) { red[wv * 2] = sum; red[wv * 2 + 1] = sq; }
        __syncthreads();
        if (t == 0) {
            const float s = red[0] + red[2] + red[4] + red[6];
            const float qq = red[1] + red[3] + red[5] + red[7];
            const float mean = s * (1.f / 512.f);
            const float var = qq * (1.f / 512.f) - mean * mean;
            mrs[0] = mean; mrs[1] = rsqrtf(var + EPS);
        }
        __syncthreads();
        const float mean = mrs[0], rstd = mrs[1];
        yL[i][t]       = fmaxf(fmaf(g3[t] * (v0 - mean), rstd, b3[t]), 0.f);
        yL[i][t + 256] = fmaxf(fmaf(g3[t + 256] * (v1 - mean), rstd, b3[t + 256]), 0.f);
        __syncthreads();
        pr[t] = w_s[t] * yL[i][s_s[t]];
        __syncthreads();
        if (t < 2) {
            float s = 0.f;
            for (int k = 0; k < FAN_IN; ++k) s += pr[t * FAN_IN + k];
            out[(size_t)(n0 + i) * 2 + t] = s + obias[t];
        }
        __syncthreads();
    }
}

// ---------------------------------------------------------------------------
extern "C" void kernel_launch(void* const* d_in, const int* in_sizes, int n_in,
                              void* d_out, int out_size, void* d_ws, size_t ws_size,
                              hipStream_t stream) {
    const float* x        = (const float*)d_in[0];
    const float* weight   = (const float*)d_in[1];
    const float* bias     = (const float*)d_in[2];
    const float* ln_gamma = (const float*)d_in[3];
    const float* ln_beta  = (const float*)d_in[4];
    const int*   edge_src = (const int*)d_in[5];
    float* out = (float*)d_out;

    // ws layout
    float* Cz1 = (float*)d_ws;                         // 4 x [512x2048]
    float* Cz2 = Cz1 + (size_t)4 * 512 * 2048;         // 4 x [512x1024]
    u16* xb    = (u16*)(Cz2 + (size_t)4 * 512 * 1024); // [512x4096] bf16
    u16* actb1 = xb + (size_t)512 * 4096;              // [512x2048] bf16
    u16* Wd    = actb1 + (size_t)512 * 2048;           // 11534336 bf16

    // 1) prep: densify W1 + x->bf16
    prep<<<2560, 256, 0, stream>>>(weight, edge_src, x, Wd, xb);
    // 2) G1 (1024 gemm units) + densify W2/W3 (1536 units)
    g1d<<<2560, 256, 0, stream>>>(xb, Wd, Cz1, weight, edge_src);
    // 3) fin1 -> actb1
    fin<2048, 4><<<512, 256, 0, stream>>>(Cz1, bias, ln_gamma, ln_beta, actb1);
    // 4) G2: Z=4 (512 blocks)
    gemm_bt<<<dim3(16, 8, 4), 256, 0, stream>>>(actb1, Wd + 8388608, Cz2,
                                                1024, 2048, 512);
    // 5) finL: fin2 + layer3 GEMV + LN3 + output -> d_out [512, 2]
    finL<<<128, 256, 0, stream>>>(Cz2, bias + 2048, ln_gamma + 2048,
                                  ln_beta + 2048, Wd + 10485760, bias + 3072,
                                  ln_gamma + 3072, ln_beta + 3072,
                                  weight, edge_src, bias + 3584, out);
}

// Round 14
// 124.002 us; speedup vs baseline: 1.2753x; 1.2753x over previous
//
#include <hip/hip_runtime.h>

// LAYER_IDX = [0, 4096, 6144, 7168, 7680, 7682]
// layer1: 4096->2048 ebase 0       | layer2: 2048->1024 ebase 262144
// layer3: 1024->512  ebase 393216  | out: 512->2        ebase 458752
#define BATCH 512
#define FAN_IN 128
#define EPS 1e-5f

typedef unsigned short u16;
typedef unsigned int u32;
typedef __attribute__((ext_vector_type(8))) short short8;   // 8 bf16
typedef __attribute__((ext_vector_type(4))) float f32x4;

__device__ __forceinline__ u16 f2bf(float f) {   // fp32->bf16 RNE
    union { float f; u32 u; } v; v.f = f;
    u32 r = v.u + 0x7fffu + ((v.u >> 16) & 1u);
    return (u16)(r >> 16);
}
__device__ __forceinline__ void ld16(const void* g, void* l) {  // async global->LDS 16B
    __builtin_amdgcn_global_load_lds(
        (const __attribute__((address_space(1))) u32*)g,
        (__attribute__((address_space(3))) u32*)l, 16, 0, 0);
}

// ---------------------------------------------------------------------------
// Densify one target node's sparse weights into a dense bf16 row (LDS scratch).
__device__ __forceinline__ void densify_node(
    float* row, int Kin, int ebase, int srcbase, u16* outrow,
    const float* __restrict__ weight, const int* __restrict__ edge_src) {
    const int t = threadIdx.x;
    for (int k = t; k < Kin; k += 256) row[k] = 0.f;
    __syncthreads();
    if (t < FAN_IN)
        atomicAdd(&row[edge_src[ebase + t] - srcbase], weight[ebase + t]);
    __syncthreads();
    for (int k0 = t * 8; k0 < Kin; k0 += 2048) {
        u16 pk[8];
#pragma unroll
        for (int i = 0; i < 8; ++i) pk[i] = f2bf(row[k0 + i]);
        *(uint4*)(outrow + k0) = *(const uint4*)pk;
    }
}

// ---------------------------------------------------------------------------
// prep: densify W1 (bf16 [m][k]) + convert x -> bf16 batch-major. 2560 blocks.
__global__ __launch_bounds__(256) void prep(
    const float* __restrict__ weight, const int* __restrict__ edge_src,
    const float* __restrict__ x, u16* __restrict__ Wd, u16* __restrict__ xb) {
    __shared__ float row[4096];
    const int bid = blockIdx.x, t = threadIdx.x;
    if (bid < 2048) {
        densify_node(row, 4096, bid * 128, 0, Wd + (size_t)bid * 4096,
                     weight, edge_src);
    } else {
        const int b = bid - 2048;
        const float* xr = x + (size_t)b * 4096;
        u16* xo = xb + (size_t)b * 4096;
        for (int k0 = t * 8; k0 < 4096; k0 += 2048) {
            const float4 f0 = *(const float4*)(xr + k0);
            const float4 f1 = *(const float4*)(xr + k0 + 4);
            uint4 pk;
            pk.x = f2bf(f0.x) | ((u32)f2bf(f0.y) << 16);
            pk.y = f2bf(f0.z) | ((u32)f2bf(f0.w) << 16);
            pk.z = f2bf(f1.x) | ((u32)f2bf(f1.y) << 16);
            pk.w = f2bf(f1.z) | ((u32)f2bf(f1.w) << 16);
            *(uint4*)(xo + k0) = pk;
        }
    }
}

// ---------------------------------------------------------------------------
// Proven partial-GEMM body (R12): Cz[z][n=batch][m=node] over K-chunk z.
// 64x64 tile, BK=32, dbuf LDS via global_load_lds, XOR swizzle, plain stores.
__device__ __forceinline__ void gemm_body(
    u16* SM, int m_t, int n_t, int z, const u16* __restrict__ Act,
    const u16* __restrict__ W, float* __restrict__ Cz, int M, int K,
    int kchunk) {
    u16* sA = SM;            // 2 x 2048 u16
    u16* sB = SM + 4096;
    const int tid = threadIdx.x;
    const int m0 = m_t * 64, n0 = n_t * 64, kbase = z * kchunk;
    float* Cp = Cz + (size_t)z * BATCH * M;

    const int r = tid >> 2, c = tid & 3;
    const int q = c ^ ((r ^ (r >> 2)) & 3);
    const u16* gA = Act + (size_t)(n0 + r) * K + kbase + q * 8;
    const u16* gB = W + (size_t)(m0 + r) * K + kbase + q * 8;
    const int lo = tid * 8;

    const int wave = tid >> 6, lane = tid & 63;
    const int l15 = lane & 15, quad = lane >> 4;
    const int aoff = (wave & 1) * 32, boff = (wave >> 1) * 32;
    int offA[2], offB[2];
#pragma unroll
    for (int i = 0; i < 2; ++i) {
        const int ra = aoff + i * 16 + l15;
        offA[i] = ra * 32 + ((quad ^ ((ra ^ (ra >> 2)) & 3)) * 8);
        const int rb = boff + i * 16 + l15;
        offB[i] = rb * 32 + ((quad ^ ((rb ^ (rb >> 2)) & 3)) * 8);
    }

    f32x4 acc[2][2] = {};
    const int niter = kchunk >> 5;
    ld16(gA, &sA[lo]); ld16(gB, &sB[lo]);
    for (int it = 0; it < niter; ++it) {
        __syncthreads();
        if (it + 1 < niter) {
            const int k0 = (it + 1) << 5;
            const int nb = ((it + 1) & 1) * 2048;
            ld16(gA + k0, &sA[nb + lo]); ld16(gB + k0, &sB[nb + lo]);
        }
        const u16* a = sA + (it & 1) * 2048;
        const u16* b = sB + (it & 1) * 2048;
        const short8 a0 = *(const short8*)(a + offA[0]);
        const short8 a1 = *(const short8*)(a + offA[1]);
        const short8 b0 = *(const short8*)(b + offB[0]);
        const short8 b1 = *(const short8*)(b + offB[1]);
        acc[0][0] = __builtin_amdgcn_mfma_f32_16x16x32_bf16(a0, b0, acc[0][0], 0, 0, 0);
        acc[0][1] = __builtin_amdgcn_mfma_f32_16x16x32_bf16(a0, b1, acc[0][1], 0, 0, 0);
        acc[1][0] = __builtin_amdgcn_mfma_f32_16x16x32_bf16(a1, b0, acc[1][0], 0, 0, 0);
        acc[1][1] = __builtin_amdgcn_mfma_f32_16x16x32_bf16(a1, b1, acc[1][1], 0, 0, 0);
    }
#pragma unroll
    for (int i = 0; i < 2; ++i) {
        const int nb = n_t * 64 + aoff + i * 16 + quad * 4;
#pragma unroll
        for (int rr = 0; rr < 4; ++rr)
#pragma unroll
            for (int j = 0; j < 2; ++j) {
                const int mg = m0 + boff + j * 16 + l15;
                Cp[(size_t)(nb + rr) * M + mg] = acc[i][j][rr];
            }
    }
}

// ---------------------------------------------------------------------------
// G1 + W2/W3 densify fused: 1D grid, 2560 blocks. (R13-proven.)
__global__ __launch_bounds__(256, 8) void g1d(
    const u16* __restrict__ xb, u16* __restrict__ Wd, float* __restrict__ Cz1,
    const float* __restrict__ weight, const int* __restrict__ edge_src) {
    __shared__ u16 SM[8192];   // 16 KB (gemm staging / densify row alias)
    const int bid = blockIdx.x;
    if (bid < 1024) {
        gemm_body(SM, bid & 31, (bid >> 5) & 7, bid >> 8, xb, Wd, Cz1,
                  2048, 4096, 1024);
    } else if (bid < 2048) {
        const int u = bid - 1024;
        densify_node((float*)SM, 2048, 262144 + u * 128, 4096,
                     Wd + 8388608 + (size_t)u * 2048, weight, edge_src);
    } else {
        const int u = bid - 2048;
        densify_node((float*)SM, 1024, 393216 + u * 128, 6144,
                     Wd + 10485760 + (size_t)u * 1024, weight, edge_src);
    }
}

// ---------------------------------------------------------------------------
// Standalone GEMM (proven 3D form): grid (M/64, 8, Z).
__global__ __launch_bounds__(256, 8) void gemm_bt(
    const u16* __restrict__ Act, const u16* __restrict__ W,
    float* __restrict__ Cz, int M, int K, int kchunk) {
    __shared__ u16 SM[8192];
    gemm_body(SM, blockIdx.x, blockIdx.y, blockIdx.z, Act, W, Cz, M, K, kchunk);
}

// ---------------------------------------------------------------------------
// fin (R12-proven): one block per batch row n. Sum Z partials + bias into an
// LDS row cache, row mean/var via shuffle reduce, LN+ReLU from LDS, write
// bf16 actb[n][m]. If WOUT: normalize in LDS and emit 2-node sparse output.
template <int M, int Z, bool WOUT>
__global__ __launch_bounds__(256) void fin(
    const float* __restrict__ Cz, const float* __restrict__ bias_l,
    const float* __restrict__ gamma_l, const float* __restrict__ beta_l,
    u16* __restrict__ actb, const float* __restrict__ weight,
    const int* __restrict__ edge_src, const float* __restrict__ obias,
    float* __restrict__ out) {
    __shared__ float rowL[M];
    __shared__ float red[8];
    __shared__ float mrs[2];
    __shared__ float w_s[256];
    __shared__ int   s_s[256];
    __shared__ float pr[256];

    const int n = blockIdx.x, t = threadIdx.x;
    const size_t zs = (size_t)BATCH * M;
    const float* base = Cz + (size_t)n * M;

    if (WOUT) { w_s[t] = weight[458752 + t]; s_s[t] = edge_src[458752 + t] - 7168; }

    float sum = 0.f, sq = 0.f;
    for (int m = t * 4; m < M; m += 1024) {
        float4 v = *(const float4*)(bias_l + m);
#pragma unroll
        for (int z = 0; z < Z; ++z) {
            const float4 cv = *(const float4*)(base + (size_t)z * zs + m);
            v.x += cv.x; v.y += cv.y; v.z += cv.z; v.w += cv.w;
        }
        *(float4*)(rowL + m) = v;
        sum += v.x + v.y + v.z + v.w;
        sq += v.x * v.x + v.y * v.y + v.z * v.z + v.w * v.w;
    }
#pragma unroll
    for (int o = 32; o; o >>= 1) { sum += __shfl_down(sum, o); sq += __shfl_down(sq, o); }
    if ((t & 63) == 0) { red[(t >> 6) * 2] = sum; red[(t >> 6) * 2 + 1] = sq; }
    __syncthreads();
    if (t == 0) {
        const float s = red[0] + red[2] + red[4] + red[6];
        const float qq = red[1] + red[3] + red[5] + red[7];
        const float mean = s / (float)M;
        const float var = qq / (float)M - mean * mean;
        mrs[0] = mean; mrs[1] = rsqrtf(var + EPS);
    }
    __syncthreads();
    const float mean = mrs[0], rstd = mrs[1];

    for (int m = t * 4; m < M; m += 1024) {
        const float4 v = *(const float4*)(rowL + m);
        const float4 g = *(const float4*)(gamma_l + m);
        const float4 bt = *(const float4*)(beta_l + m);
        const float o0 = fmaxf(fmaf(g.x * (v.x - mean), rstd, bt.x), 0.f);
        const float o1 = fmaxf(fmaf(g.y * (v.y - mean), rstd, bt.y), 0.f);
        const float o2 = fmaxf(fmaf(g.z * (v.z - mean), rstd, bt.z), 0.f);
        const float o3 = fmaxf(fmaf(g.w * (v.w - mean), rstd, bt.w), 0.f);
        if (WOUT) {
            rowL[m + 0] = o0; rowL[m + 1] = o1; rowL[m + 2] = o2; rowL[m + 3] = o3;
        } else {
            u16 pk[4] = {f2bf(o0), f2bf(o1), f2bf(o2), f2bf(o3)};
            *(uint2*)(actb + (size_t)n * M + m) = *(const uint2*)pk;
        }
    }
    if (WOUT) {   // sparse output layer from the post-LN row in LDS
        __syncthreads();
        pr[t] = w_s[t] * rowL[s_s[t]];
        __syncthreads();
        if (t < 2) {
            float s = 0.f;
            for (int k = 0; k < FAN_IN; ++k) s += pr[t * FAN_IN + k];
            out[(size_t)n * 2 + t] = s + obias[t];
        }
    }
}

// ---------------------------------------------------------------------------
extern "C" void kernel_launch(void* const* d_in, const int* in_sizes, int n_in,
                              void* d_out, int out_size, void* d_ws, size_t ws_size,
                              hipStream_t stream) {
    const float* x        = (const float*)d_in[0];
    const float* weight   = (const float*)d_in[1];
    const float* bias     = (const float*)d_in[2];
    const float* ln_gamma = (const float*)d_in[3];
    const float* ln_beta  = (const float*)d_in[4];
    const int*   edge_src = (const int*)d_in[5];
    float* out = (float*)d_out;

    // ws layout: Cz batch-major [z][512][M]
    float* Cz1 = (float*)d_ws;                         // 4 x [512x2048]
    float* Cz2 = Cz1 + (size_t)4 * 512 * 2048;         // 4 x [512x1024]
    float* Cz3 = Cz2 + (size_t)4 * 512 * 1024;         // 8 x [512x512]
    u16* xb    = (u16*)(Cz3 + (size_t)8 * 512 * 512);  // [512x4096] bf16
    u16* actb1 = xb + (size_t)512 * 4096;              // [512x2048] bf16
    u16* actb2 = actb1 + (size_t)512 * 2048;           // [512x1024] bf16
    u16* Wd    = actb2 + (size_t)512 * 1024;           // 11534336 bf16

    // 1) prep: densify W1 + x->bf16
    prep<<<2560, 256, 0, stream>>>(weight, edge_src, x, Wd, xb);
    // 2) G1 (1024 gemm units) + densify W2/W3 (1536 units, rides along)
    g1d<<<2560, 256, 0, stream>>>(xb, Wd, Cz1, weight, edge_src);
    // 3) fin1 -> actb1
    fin<2048, 4, false><<<512, 256, 0, stream>>>(
        Cz1, bias, ln_gamma, ln_beta, actb1, nullptr, nullptr, nullptr, nullptr);
    // 4) G2: Z=4 (512 blocks)
    gemm_bt<<<dim3(16, 8, 4), 256, 0, stream>>>(actb1, Wd + 8388608, Cz2,
                                                1024, 2048, 512);
    // 5) fin2 -> actb2
    fin<1024, 4, false><<<512, 256, 0, stream>>>(
        Cz2, bias + 2048, ln_gamma + 2048, ln_beta + 2048, actb2,
        nullptr, nullptr, nullptr, nullptr);
    // 6) G3: Z=8 (512 blocks)
    gemm_bt<<<dim3(8, 8, 8), 256, 0, stream>>>(actb2, Wd + 10485760, Cz3,
                                               512, 1024, 128);
    // 7) fin3 + sparse output layer -> d_out [512, 2]
    fin<512, 8, true><<<512, 256, 0, stream>>>(
        Cz3, bias + 3072, ln_gamma + 3072, ln_beta + 3072, nullptr,
        weight, edge_src, bias + 3584, out);
}

// Round 15
// 121.230 us; speedup vs baseline: 1.3044x; 1.0229x over previous
//
#include <hip/hip_runtime.h>

// LAYER_IDX = [0, 4096, 6144, 7168, 7680, 7682]
// layer1: 4096->2048 ebase 0       | layer2: 2048->1024 ebase 262144
// layer3: 1024->512  ebase 393216  | out: 512->2        ebase 458752
#define BATCH 512
#define FAN_IN 128
#define EPS 1e-5f

typedef unsigned short u16;
typedef unsigned int u32;
typedef __attribute__((ext_vector_type(8))) short short8;   // 8 bf16
typedef __attribute__((ext_vector_type(4))) float f32x4;

__device__ __forceinline__ u16 f2bf(float f) {   // fp32->bf16 RNE
    union { float f; u32 u; } v; v.f = f;
    u32 r = v.u + 0x7fffu + ((v.u >> 16) & 1u);
    return (u16)(r >> 16);
}
__device__ __forceinline__ void ld16(const void* g, void* l) {  // async global->LDS 16B
    __builtin_amdgcn_global_load_lds(
        (const __attribute__((address_space(1))) u32*)g,
        (__attribute__((address_space(3))) u32*)l, 16, 0, 0);
}

// ---------------------------------------------------------------------------
// Densify one target node's sparse weights into a dense bf16 row (LDS scratch).
__device__ __forceinline__ void densify_node(
    float* row, int Kin, int ebase, int srcbase, u16* outrow,
    const float* __restrict__ weight, const int* __restrict__ edge_src) {
    const int t = threadIdx.x;
    for (int k = t; k < Kin; k += 256) row[k] = 0.f;
    __syncthreads();
    if (t < FAN_IN)
        atomicAdd(&row[edge_src[ebase + t] - srcbase], weight[ebase + t]);
    __syncthreads();
    for (int k0 = t * 8; k0 < Kin; k0 += 2048) {
        u16 pk[8];
#pragma unroll
        for (int i = 0; i < 8; ++i) pk[i] = f2bf(row[k0 + i]);
        *(uint4*)(outrow + k0) = *(const uint4*)pk;
    }
}

// ---------------------------------------------------------------------------
// prep: densify W1 (bf16 [m][k]) + convert x -> bf16 batch-major. 2560 blocks.
__global__ __launch_bounds__(256) void prep(
    const float* __restrict__ weight, const int* __restrict__ edge_src,
    const float* __restrict__ x, u16* __restrict__ Wd, u16* __restrict__ xb) {
    __shared__ float row[4096];
    const int bid = blockIdx.x, t = threadIdx.x;
    if (bid < 2048) {
        densify_node(row, 4096, bid * 128, 0, Wd + (size_t)bid * 4096,
                     weight, edge_src);
    } else {
        const int b = bid - 2048;
        const float* xr = x + (size_t)b * 4096;
        u16* xo = xb + (size_t)b * 4096;
        for (int k0 = t * 8; k0 < 4096; k0 += 2048) {
            const float4 f0 = *(const float4*)(xr + k0);
            const float4 f1 = *(const float4*)(xr + k0 + 4);
            uint4 pk;
            pk.x = f2bf(f0.x) | ((u32)f2bf(f0.y) << 16);
            pk.y = f2bf(f0.z) | ((u32)f2bf(f0.w) << 16);
            pk.z = f2bf(f1.x) | ((u32)f2bf(f1.y) << 16);
            pk.w = f2bf(f1.z) | ((u32)f2bf(f1.w) << 16);
            *(uint4*)(xo + k0) = pk;
        }
    }
}

// ---------------------------------------------------------------------------
// 64x64 partial-GEMM body (R12-proven): Cz[z][n][m] over K-chunk z.
__device__ __forceinline__ void gemm_body(
    u16* SM, int m_t, int n_t, int z, const u16* __restrict__ Act,
    const u16* __restrict__ W, float* __restrict__ Cz, int M, int K,
    int kchunk) {
    u16* sA = SM;            // 2 x 2048 u16
    u16* sB = SM + 4096;
    const int tid = threadIdx.x;
    const int m0 = m_t * 64, n0 = n_t * 64, kbase = z * kchunk;
    float* Cp = Cz + (size_t)z * BATCH * M;

    const int r = tid >> 2, c = tid & 3;
    const int q = c ^ ((r ^ (r >> 2)) & 3);
    const u16* gA = Act + (size_t)(n0 + r) * K + kbase + q * 8;
    const u16* gB = W + (size_t)(m0 + r) * K + kbase + q * 8;
    const int lo = tid * 8;

    const int wave = tid >> 6, lane = tid & 63;
    const int l15 = lane & 15, quad = lane >> 4;
    const int aoff = (wave & 1) * 32, boff = (wave >> 1) * 32;
    int offA[2], offB[2];
#pragma unroll
    for (int i = 0; i < 2; ++i) {
        const int ra = aoff + i * 16 + l15;
        offA[i] = ra * 32 + ((quad ^ ((ra ^ (ra >> 2)) & 3)) * 8);
        const int rb = boff + i * 16 + l15;
        offB[i] = rb * 32 + ((quad ^ ((rb ^ (rb >> 2)) & 3)) * 8);
    }

    f32x4 acc[2][2] = {};
    const int niter = kchunk >> 5;
    ld16(gA, &sA[lo]); ld16(gB, &sB[lo]);
    for (int it = 0; it < niter; ++it) {
        __syncthreads();
        if (it + 1 < niter) {
            const int k0 = (it + 1) << 5;
            const int nb = ((it + 1) & 1) * 2048;
            ld16(gA + k0, &sA[nb + lo]); ld16(gB + k0, &sB[nb + lo]);
        }
        const u16* a = sA + (it & 1) * 2048;
        const u16* b = sB + (it & 1) * 2048;
        const short8 a0 = *(const short8*)(a + offA[0]);
        const short8 a1 = *(const short8*)(a + offA[1]);
        const short8 b0 = *(const short8*)(b + offB[0]);
        const short8 b1 = *(const short8*)(b + offB[1]);
        acc[0][0] = __builtin_amdgcn_mfma_f32_16x16x32_bf16(a0, b0, acc[0][0], 0, 0, 0);
        acc[0][1] = __builtin_amdgcn_mfma_f32_16x16x32_bf16(a0, b1, acc[0][1], 0, 0, 0);
        acc[1][0] = __builtin_amdgcn_mfma_f32_16x16x32_bf16(a1, b0, acc[1][0], 0, 0, 0);
        acc[1][1] = __builtin_amdgcn_mfma_f32_16x16x32_bf16(a1, b1, acc[1][1], 0, 0, 0);
    }
#pragma unroll
    for (int i = 0; i < 2; ++i) {
        const int nb = n_t * 64 + aoff + i * 16 + quad * 4;
#pragma unroll
        for (int rr = 0; rr < 4; ++rr)
#pragma unroll
            for (int j = 0; j < 2; ++j) {
                const int mg = m0 + boff + j * 16 + l15;
                Cp[(size_t)(nb + rr) * M + mg] = acc[i][j][rr];
            }
    }
}

// ---------------------------------------------------------------------------
// 128x128 partial-GEMM body (m97 shape): 4 waves of 64x64, acc[4][4].
// 2 MFMAs per ds_read_b128, 256 B staging/MFMA. LDS 32 KB (2 bufs x 16 KB).
__device__ __forceinline__ void gemm128_body(
    u16* SM, int m_t, int n_t, int z, const u16* __restrict__ Act,
    const u16* __restrict__ W, float* __restrict__ Cz, int M, int K,
    int kchunk) {
    u16* sA = SM;             // 2 bufs x 4096 u16 (128 rows x 32 k)
    u16* sB = SM + 8192;
    const int tid = threadIdx.x;
    const int m0 = m_t * 128, n0 = n_t * 128, kbase = z * kchunk;
    float* Cp = Cz + (size_t)z * BATCH * M;

    // staging: thread owns LDS slots tid (rows 0..63) and tid+256 (rows 64..127)
    const int r = tid >> 2, c = tid & 3;
    const int q1 = c ^ ((r ^ (r >> 2)) & 3);
    const int r2 = r + 64;
    const int q2 = c ^ ((r2 ^ (r2 >> 2)) & 3);
    const u16* gA1 = Act + (size_t)(n0 + r) * K + kbase + q1 * 8;
    const u16* gA2 = Act + (size_t)(n0 + r2) * K + kbase + q2 * 8;
    const u16* gB1 = W + (size_t)(m0 + r) * K + kbase + q1 * 8;
    const u16* gB2 = W + (size_t)(m0 + r2) * K + kbase + q2 * 8;
    const int lo1 = tid * 8, lo2 = tid * 8 + 2048;

    const int wave = tid >> 6, lane = tid & 63;
    const int l15 = lane & 15, quad = lane >> 4;
    const int wn = (wave & 1) * 64, wm = (wave >> 1) * 64;
    int offA[4], offB[4];
#pragma unroll
    for (int i = 0; i < 4; ++i) {
        const int na = wn + i * 16 + l15;
        offA[i] = na * 32 + ((quad ^ ((na ^ (na >> 2)) & 3)) * 8);
        const int mb = wm + i * 16 + l15;
        offB[i] = mb * 32 + ((quad ^ ((mb ^ (mb >> 2)) & 3)) * 8);
    }

    f32x4 acc[4][4] = {};
    const int niter = kchunk >> 5;
    ld16(gA1, &sA[lo1]); ld16(gA2, &sA[lo2]);
    ld16(gB1, &sB[lo1]); ld16(gB2, &sB[lo2]);
    for (int it = 0; it < niter; ++it) {
        __syncthreads();
        if (it + 1 < niter) {
            const int k0 = (it + 1) << 5;
            const int nb = ((it + 1) & 1) * 4096;
            ld16(gA1 + k0, &sA[nb + lo1]); ld16(gA2 + k0, &sA[nb + lo2]);
            ld16(gB1 + k0, &sB[nb + lo1]); ld16(gB2 + k0, &sB[nb + lo2]);
        }
        const u16* a = sA + (it & 1) * 4096;
        const u16* b = sB + (it & 1) * 4096;
        short8 av[4], bv[4];
#pragma unroll
        for (int i = 0; i < 4; ++i) av[i] = *(const short8*)(a + offA[i]);
#pragma unroll
        for (int j = 0; j < 4; ++j) bv[j] = *(const short8*)(b + offB[j]);
#pragma unroll
        for (int i = 0; i < 4; ++i)
#pragma unroll
            for (int j = 0; j < 4; ++j)
                acc[i][j] = __builtin_amdgcn_mfma_f32_16x16x32_bf16(
                    av[i], bv[j], acc[i][j], 0, 0, 0);
    }
#pragma unroll
    for (int i = 0; i < 4; ++i) {
        const int nb = n0 + wn + i * 16 + quad * 4;
#pragma unroll
        for (int rr = 0; rr < 4; ++rr)
#pragma unroll
            for (int j = 0; j < 4; ++j) {
                const int mg = m0 + wm + j * 16 + l15;
                Cp[(size_t)(nb + rr) * M + mg] = acc[i][j][rr];
            }
    }
}

// ---------------------------------------------------------------------------
// G1 (128x128 tiles, Z=8) + W2/W3 densify fused: 1D grid, 2048 blocks.
//  bid < 512           : G1 gemm unit (16m' x 4n' x 8z, kchunk 512)
//  512 <= bid < 1536   : densify W2 node (Kin 2048)
//  1536 <= bid < 2048  : densify W3 node (Kin 1024)
__global__ __launch_bounds__(256) void g1d(
    const u16* __restrict__ xb, u16* __restrict__ Wd, float* __restrict__ Cz1,
    const float* __restrict__ weight, const int* __restrict__ edge_src) {
    __shared__ u16 SM[16384];   // 32 KB (gemm staging / densify row alias)
    const int bid = blockIdx.x;
    if (bid < 512) {
        gemm128_body(SM, bid & 15, (bid >> 4) & 3, bid >> 6, xb, Wd, Cz1,
                     2048, 4096, 512);
    } else if (bid < 1536) {
        const int u = bid - 512;
        densify_node((float*)SM, 2048, 262144 + u * 128, 4096,
                     Wd + 8388608 + (size_t)u * 2048, weight, edge_src);
    } else {
        const int u = bid - 1536;
        densify_node((float*)SM, 1024, 393216 + u * 128, 6144,
                     Wd + 10485760 + (size_t)u * 1024, weight, edge_src);
    }
}

// ---------------------------------------------------------------------------
// Standalone 64x64 GEMM (proven 3D form): grid (M/64, 8, Z).
__global__ __launch_bounds__(256, 8) void gemm_bt(
    const u16* __restrict__ Act, const u16* __restrict__ W,
    float* __restrict__ Cz, int M, int K, int kchunk) {
    __shared__ u16 SM[8192];
    gemm_body(SM, blockIdx.x, blockIdx.y, blockIdx.z, Act, W, Cz, M, K, kchunk);
}

// ---------------------------------------------------------------------------
// fin (R12-proven): one block per batch row n. Sum Z partials + bias into an
// LDS row cache, row mean/var via shuffle reduce, LN+ReLU from LDS, write
// bf16 actb[n][m]. If WOUT: normalize in LDS and emit 2-node sparse output.
template <int M, int Z, bool WOUT>
__global__ __launch_bounds__(256) void fin(
    const float* __restrict__ Cz, const float* __restrict__ bias_l,
    const float* __restrict__ gamma_l, const float* __restrict__ beta_l,
    u16* __restrict__ actb, const float* __restrict__ weight,
    const int* __restrict__ edge_src, const float* __restrict__ obias,
    float* __restrict__ out) {
    __shared__ float rowL[M];
    __shared__ float red[8];
    __shared__ float mrs[2];
    __shared__ float w_s[256];
    __shared__ int   s_s[256];
    __shared__ float pr[256];

    const int n = blockIdx.x, t = threadIdx.x;
    const size_t zs = (size_t)BATCH * M;
    const float* base = Cz + (size_t)n * M;

    if (WOUT) { w_s[t] = weight[458752 + t]; s_s[t] = edge_src[458752 + t] - 7168; }

    float sum = 0.f, sq = 0.f;
    for (int m = t * 4; m < M; m += 1024) {
        float4 v = *(const float4*)(bias_l + m);
#pragma unroll
        for (int z = 0; z < Z; ++z) {
            const float4 cv = *(const float4*)(base + (size_t)z * zs + m);
            v.x += cv.x; v.y += cv.y; v.z += cv.z; v.w += cv.w;
        }
        *(float4*)(rowL + m) = v;
        sum += v.x + v.y + v.z + v.w;
        sq += v.x * v.x + v.y * v.y + v.z * v.z + v.w * v.w;
    }
#pragma unroll
    for (int o = 32; o; o >>= 1) { sum += __shfl_down(sum, o); sq += __shfl_down(sq, o); }
    if ((t & 63) == 0) { red[(t >> 6) * 2] = sum; red[(t >> 6) * 2 + 1] = sq; }
    __syncthreads();
    if (t == 0) {
        const float s = red[0] + red[2] + red[4] + red[6];
        const float qq = red[1] + red[3] + red[5] + red[7];
        const float mean = s / (float)M;
        const float var = qq / (float)M - mean * mean;
        mrs[0] = mean; mrs[1] = rsqrtf(var + EPS);
    }
    __syncthreads();
    const float mean = mrs[0], rstd = mrs[1];

    for (int m = t * 4; m < M; m += 1024) {
        const float4 v = *(const float4*)(rowL + m);
        const float4 g = *(const float4*)(gamma_l + m);
        const float4 bt = *(const float4*)(beta_l + m);
        const float o0 = fmaxf(fmaf(g.x * (v.x - mean), rstd, bt.x), 0.f);
        const float o1 = fmaxf(fmaf(g.y * (v.y - mean), rstd, bt.y), 0.f);
        const float o2 = fmaxf(fmaf(g.z * (v.z - mean), rstd, bt.z), 0.f);
        const float o3 = fmaxf(fmaf(g.w * (v.w - mean), rstd, bt.w), 0.f);
        if (WOUT) {
            rowL[m + 0] = o0; rowL[m + 1] = o1; rowL[m + 2] = o2; rowL[m + 3] = o3;
        } else {
            u16 pk[4] = {f2bf(o0), f2bf(o1), f2bf(o2), f2bf(o3)};
            *(uint2*)(actb + (size_t)n * M + m) = *(const uint2*)pk;
        }
    }
    if (WOUT) {   // sparse output layer from the post-LN row in LDS
        __syncthreads();
        pr[t] = w_s[t] * rowL[s_s[t]];
        __syncthreads();
        if (t < 2) {
            float s = 0.f;
            for (int k = 0; k < FAN_IN; ++k) s += pr[t * FAN_IN + k];
            out[(size_t)n * 2 + t] = s + obias[t];
        }
    }
}

// ---------------------------------------------------------------------------
extern "C" void kernel_launch(void* const* d_in, const int* in_sizes, int n_in,
                              void* d_out, int out_size, void* d_ws, size_t ws_size,
                              hipStream_t stream) {
    const float* x        = (const float*)d_in[0];
    const float* weight   = (const float*)d_in[1];
    const float* bias     = (const float*)d_in[2];
    const float* ln_gamma = (const float*)d_in[3];
    const float* ln_beta  = (const float*)d_in[4];
    const int*   edge_src = (const int*)d_in[5];
    float* out = (float*)d_out;

    // ws layout: Cz batch-major [z][512][M]
    float* Cz1 = (float*)d_ws;                         // 8 x [512x2048]
    float* Cz2 = Cz1 + (size_t)8 * 512 * 2048;         // 4 x [512x1024]
    float* Cz3 = Cz2 + (size_t)4 * 512 * 1024;         // 8 x [512x512]
    u16* xb    = (u16*)(Cz3 + (size_t)8 * 512 * 512);  // [512x4096] bf16
    u16* actb1 = xb + (size_t)512 * 4096;              // [512x2048] bf16
    u16* actb2 = actb1 + (size_t)512 * 2048;           // [512x1024] bf16
    u16* Wd    = actb2 + (size_t)512 * 1024;           // 11534336 bf16

    // 1) prep: densify W1 + x->bf16
    prep<<<2560, 256, 0, stream>>>(weight, edge_src, x, Wd, xb);
    // 2) G1 (512 gemm units, 128x128, Z=8) + densify W2/W3 (1536 units)
    g1d<<<2048, 256, 0, stream>>>(xb, Wd, Cz1, weight, edge_src);
    // 3) fin1 (Z=8) -> actb1
    fin<2048, 8, false><<<512, 256, 0, stream>>>(
        Cz1, bias, ln_gamma, ln_beta, actb1, nullptr, nullptr, nullptr, nullptr);
    // 4) G2: 64x64, Z=4 (512 blocks)
    gemm_bt<<<dim3(16, 8, 4), 256, 0, stream>>>(actb1, Wd + 8388608, Cz2,
                                                1024, 2048, 512);
    // 5) fin2 -> actb2
    fin<1024, 4, false><<<512, 256, 0, stream>>>(
        Cz2, bias + 2048, ln_gamma + 2048, ln_beta + 2048, actb2,
        nullptr, nullptr, nullptr, nullptr);
    // 6) G3: 64x64, Z=8 (512 blocks)
    gemm_bt<<<dim3(8, 8, 8), 256, 0, stream>>>(actb2, Wd + 10485760, Cz3,
                                               512, 1024, 128);
    // 7) fin3 + sparse output layer -> d_out [512, 2]
    fin<512, 8, true><<<512, 256, 0, stream>>>(
        Cz3, bias + 3072, ln_gamma + 3072, ln_beta + 3072, nullptr,
        weight, edge_src, bias + 3584, out);
}

// Round 16
// 120.273 us; speedup vs baseline: 1.3148x; 1.0080x over previous
//
#include <hip/hip_runtime.h>

// LAYER_IDX = [0, 4096, 6144, 7168, 7680, 7682]
// layer1: 4096->2048 ebase 0       | layer2: 2048->1024 ebase 262144
// layer3: 1024->512  ebase 393216  | out: 512->2        ebase 458752
#define BATCH 512
#define FAN_IN 128
#define EPS 1e-5f

typedef unsigned short u16;
typedef unsigned int u32;
typedef _Float16 f16;
typedef __attribute__((ext_vector_type(8))) short short8;   // 8 bf16
typedef __attribute__((ext_vector_type(4))) float f32x4;
typedef __attribute__((ext_vector_type(4))) _Float16 f16x4;

__device__ __forceinline__ u16 f2bf(float f) {   // fp32->bf16 RNE
    union { float f; u32 u; } v; v.f = f;
    u32 r = v.u + 0x7fffu + ((v.u >> 16) & 1u);
    return (u16)(r >> 16);
}
__device__ __forceinline__ void ld16(const void* g, void* l) {  // async global->LDS 16B
    __builtin_amdgcn_global_load_lds(
        (const __attribute__((address_space(1))) u32*)g,
        (__attribute__((address_space(3))) u32*)l, 16, 0, 0);
}

// ---------------------------------------------------------------------------
// Densify one target node's sparse weights into a dense bf16 row (LDS scratch).
__device__ __forceinline__ void densify_node(
    float* row, int Kin, int ebase, int srcbase, u16* outrow,
    const float* __restrict__ weight, const int* __restrict__ edge_src) {
    const int t = threadIdx.x;
    for (int k = t; k < Kin; k += 256) row[k] = 0.f;
    __syncthreads();
    if (t < FAN_IN)
        atomicAdd(&row[edge_src[ebase + t] - srcbase], weight[ebase + t]);
    __syncthreads();
    for (int k0 = t * 8; k0 < Kin; k0 += 2048) {
        u16 pk[8];
#pragma unroll
        for (int i = 0; i < 8; ++i) pk[i] = f2bf(row[k0 + i]);
        *(uint4*)(outrow + k0) = *(const uint4*)pk;
    }
}

// ---------------------------------------------------------------------------
// prep: densify W1 (bf16 [m][k]) + convert x -> bf16 batch-major. 2560 blocks.
__global__ __launch_bounds__(256) void prep(
    const float* __restrict__ weight, const int* __restrict__ edge_src,
    const float* __restrict__ x, u16* __restrict__ Wd, u16* __restrict__ xb) {
    __shared__ float row[4096];
    const int bid = blockIdx.x, t = threadIdx.x;
    if (bid < 2048) {
        densify_node(row, 4096, bid * 128, 0, Wd + (size_t)bid * 4096,
                     weight, edge_src);
    } else {
        const int b = bid - 2048;
        const float* xr = x + (size_t)b * 4096;
        u16* xo = xb + (size_t)b * 4096;
        for (int k0 = t * 8; k0 < 4096; k0 += 2048) {
            const float4 f0 = *(const float4*)(xr + k0);
            const float4 f1 = *(const float4*)(xr + k0 + 4);
            uint4 pk;
            pk.x = f2bf(f0.x) | ((u32)f2bf(f0.y) << 16);
            pk.y = f2bf(f0.z) | ((u32)f2bf(f0.w) << 16);
            pk.z = f2bf(f1.x) | ((u32)f2bf(f1.y) << 16);
            pk.w = f2bf(f1.z) | ((u32)f2bf(f1.w) << 16);
            *(uint4*)(xo + k0) = pk;
        }
    }
}

// ---------------------------------------------------------------------------
// 64x64 partial-GEMM body: Cz[z][n][m] (fp16 partials) over K-chunk z.
__device__ __forceinline__ void gemm_body(
    u16* SM, int m_t, int n_t, int z, const u16* __restrict__ Act,
    const u16* __restrict__ W, f16* __restrict__ Cz, int M, int K,
    int kchunk) {
    u16* sA = SM;            // 2 x 2048 u16
    u16* sB = SM + 4096;
    const int tid = threadIdx.x;
    const int m0 = m_t * 64, n0 = n_t * 64, kbase = z * kchunk;
    f16* Cp = Cz + (size_t)z * BATCH * M;

    const int r = tid >> 2, c = tid & 3;
    const int q = c ^ ((r ^ (r >> 2)) & 3);
    const u16* gA = Act + (size_t)(n0 + r) * K + kbase + q * 8;
    const u16* gB = W + (size_t)(m0 + r) * K + kbase + q * 8;
    const int lo = tid * 8;

    const int wave = tid >> 6, lane = tid & 63;
    const int l15 = lane & 15, quad = lane >> 4;
    const int aoff = (wave & 1) * 32, boff = (wave >> 1) * 32;
    int offA[2], offB[2];
#pragma unroll
    for (int i = 0; i < 2; ++i) {
        const int ra = aoff + i * 16 + l15;
        offA[i] = ra * 32 + ((quad ^ ((ra ^ (ra >> 2)) & 3)) * 8);
        const int rb = boff + i * 16 + l15;
        offB[i] = rb * 32 + ((quad ^ ((rb ^ (rb >> 2)) & 3)) * 8);
    }

    f32x4 acc[2][2] = {};
    const int niter = kchunk >> 5;
    ld16(gA, &sA[lo]); ld16(gB, &sB[lo]);
    for (int it = 0; it < niter; ++it) {
        __syncthreads();
        if (it + 1 < niter) {
            const int k0 = (it + 1) << 5;
            const int nb = ((it + 1) & 1) * 2048;
            ld16(gA + k0, &sA[nb + lo]); ld16(gB + k0, &sB[nb + lo]);
        }
        const u16* a = sA + (it & 1) * 2048;
        const u16* b = sB + (it & 1) * 2048;
        const short8 a0 = *(const short8*)(a + offA[0]);
        const short8 a1 = *(const short8*)(a + offA[1]);
        const short8 b0 = *(const short8*)(b + offB[0]);
        const short8 b1 = *(const short8*)(b + offB[1]);
        acc[0][0] = __builtin_amdgcn_mfma_f32_16x16x32_bf16(a0, b0, acc[0][0], 0, 0, 0);
        acc[0][1] = __builtin_amdgcn_mfma_f32_16x16x32_bf16(a0, b1, acc[0][1], 0, 0, 0);
        acc[1][0] = __builtin_amdgcn_mfma_f32_16x16x32_bf16(a1, b0, acc[1][0], 0, 0, 0);
        acc[1][1] = __builtin_amdgcn_mfma_f32_16x16x32_bf16(a1, b1, acc[1][1], 0, 0, 0);
    }
#pragma unroll
    for (int i = 0; i < 2; ++i) {
        const int nb = n_t * 64 + aoff + i * 16 + quad * 4;
#pragma unroll
        for (int rr = 0; rr < 4; ++rr)
#pragma unroll
            for (int j = 0; j < 2; ++j) {
                const int mg = m0 + boff + j * 16 + l15;
                Cp[(size_t)(nb + rr) * M + mg] = (f16)acc[i][j][rr];
            }
    }
}

// ---------------------------------------------------------------------------
// 128x128 partial-GEMM body (m97 shape): 4 waves of 64x64, acc[4][4].
__device__ __forceinline__ void gemm128_body(
    u16* SM, int m_t, int n_t, int z, const u16* __restrict__ Act,
    const u16* __restrict__ W, f16* __restrict__ Cz, int M, int K,
    int kchunk) {
    u16* sA = SM;             // 2 bufs x 4096 u16 (128 rows x 32 k)
    u16* sB = SM + 8192;
    const int tid = threadIdx.x;
    const int m0 = m_t * 128, n0 = n_t * 128, kbase = z * kchunk;
    f16* Cp = Cz + (size_t)z * BATCH * M;

    const int r = tid >> 2, c = tid & 3;
    const int q1 = c ^ ((r ^ (r >> 2)) & 3);
    const int r2 = r + 64;
    const int q2 = c ^ ((r2 ^ (r2 >> 2)) & 3);
    const u16* gA1 = Act + (size_t)(n0 + r) * K + kbase + q1 * 8;
    const u16* gA2 = Act + (size_t)(n0 + r2) * K + kbase + q2 * 8;
    const u16* gB1 = W + (size_t)(m0 + r) * K + kbase + q1 * 8;
    const u16* gB2 = W + (size_t)(m0 + r2) * K + kbase + q2 * 8;
    const int lo1 = tid * 8, lo2 = tid * 8 + 2048;

    const int wave = tid >> 6, lane = tid & 63;
    const int l15 = lane & 15, quad = lane >> 4;
    const int wn = (wave & 1) * 64, wm = (wave >> 1) * 64;
    int offA[4], offB[4];
#pragma unroll
    for (int i = 0; i < 4; ++i) {
        const int na = wn + i * 16 + l15;
        offA[i] = na * 32 + ((quad ^ ((na ^ (na >> 2)) & 3)) * 8);
        const int mb = wm + i * 16 + l15;
        offB[i] = mb * 32 + ((quad ^ ((mb ^ (mb >> 2)) & 3)) * 8);
    }

    f32x4 acc[4][4] = {};
    const int niter = kchunk >> 5;
    ld16(gA1, &sA[lo1]); ld16(gA2, &sA[lo2]);
    ld16(gB1, &sB[lo1]); ld16(gB2, &sB[lo2]);
    for (int it = 0; it < niter; ++it) {
        __syncthreads();
        if (it + 1 < niter) {
            const int k0 = (it + 1) << 5;
            const int nb = ((it + 1) & 1) * 4096;
            ld16(gA1 + k0, &sA[nb + lo1]); ld16(gA2 + k0, &sA[nb + lo2]);
            ld16(gB1 + k0, &sB[nb + lo1]); ld16(gB2 + k0, &sB[nb + lo2]);
        }
        const u16* a = sA + (it & 1) * 4096;
        const u16* b = sB + (it & 1) * 4096;
        short8 av[4], bv[4];
#pragma unroll
        for (int i = 0; i < 4; ++i) av[i] = *(const short8*)(a + offA[i]);
#pragma unroll
        for (int j = 0; j < 4; ++j) bv[j] = *(const short8*)(b + offB[j]);
#pragma unroll
        for (int i = 0; i < 4; ++i)
#pragma unroll
            for (int j = 0; j < 4; ++j)
                acc[i][j] = __builtin_amdgcn_mfma_f32_16x16x32_bf16(
                    av[i], bv[j], acc[i][j], 0, 0, 0);
    }
#pragma unroll
    for (int i = 0; i < 4; ++i) {
        const int nb = n0 + wn + i * 16 + quad * 4;
#pragma unroll
        for (int rr = 0; rr < 4; ++rr)
#pragma unroll
            for (int j = 0; j < 4; ++j) {
                const int mg = m0 + wm + j * 16 + l15;
                Cp[(size_t)(nb + rr) * M + mg] = (f16)acc[i][j][rr];
            }
    }
}

// ---------------------------------------------------------------------------
// G1 (128x128 tiles, Z=8) + W2/W3 densify fused: 1D grid, 2048 blocks.
__global__ __launch_bounds__(256) void g1d(
    const u16* __restrict__ xb, u16* __restrict__ Wd, f16* __restrict__ Cz1,
    const float* __restrict__ weight, const int* __restrict__ edge_src) {
    __shared__ u16 SM[16384];   // 32 KB (gemm staging / densify row alias)
    const int bid = blockIdx.x;
    if (bid < 512) {
        gemm128_body(SM, bid & 15, (bid >> 4) & 3, bid >> 6, xb, Wd, Cz1,
                     2048, 4096, 512);
    } else if (bid < 1536) {
        const int u = bid - 512;
        densify_node((float*)SM, 2048, 262144 + u * 128, 4096,
                     Wd + 8388608 + (size_t)u * 2048, weight, edge_src);
    } else {
        const int u = bid - 1536;
        densify_node((float*)SM, 1024, 393216 + u * 128, 6144,
                     Wd + 10485760 + (size_t)u * 1024, weight, edge_src);
    }
}

// ---------------------------------------------------------------------------
// Standalone 64x64 GEMM (3D form): grid (M/64, 8, Z).
__global__ __launch_bounds__(256, 8) void gemm_bt(
    const u16* __restrict__ Act, const u16* __restrict__ W,
    f16* __restrict__ Cz, int M, int K, int kchunk) {
    __shared__ u16 SM[8192];
    gemm_body(SM, blockIdx.x, blockIdx.y, blockIdx.z, Act, W, Cz, M, K, kchunk);
}

// ---------------------------------------------------------------------------
// fin: one block per batch row n. Sum Z fp16 partials + bias into an LDS row
// (fp32 accumulate), row mean/var via shuffle reduce, LN+ReLU from LDS, write
// bf16 actb[n][m]. If WOUT: normalize in LDS and emit 2-node sparse output.
template <int M, int Z, bool WOUT>
__global__ __launch_bounds__(256) void fin(
    const f16* __restrict__ Cz, const float* __restrict__ bias_l,
    const float* __restrict__ gamma_l, const float* __restrict__ beta_l,
    u16* __restrict__ actb, const float* __restrict__ weight,
    const int* __restrict__ edge_src, const float* __restrict__ obias,
    float* __restrict__ out) {
    __shared__ float rowL[M];
    __shared__ float red[8];
    __shared__ float mrs[2];
    __shared__ float w_s[256];
    __shared__ int   s_s[256];
    __shared__ float pr[256];

    const int n = blockIdx.x, t = threadIdx.x;
    const size_t zs = (size_t)BATCH * M;
    const f16* base = Cz + (size_t)n * M;

    if (WOUT) { w_s[t] = weight[458752 + t]; s_s[t] = edge_src[458752 + t] - 7168; }

    float sum = 0.f, sq = 0.f;
    for (int m = t * 4; m < M; m += 1024) {
        float4 v = *(const float4*)(bias_l + m);
#pragma unroll
        for (int z = 0; z < Z; ++z) {
            const f16x4 cv = *(const f16x4*)(base + (size_t)z * zs + m);
            v.x += (float)cv.x; v.y += (float)cv.y;
            v.z += (float)cv.z; v.w += (float)cv.w;
        }
        *(float4*)(rowL + m) = v;
        sum += v.x + v.y + v.z + v.w;
        sq += v.x * v.x + v.y * v.y + v.z * v.z + v.w * v.w;
    }
#pragma unroll
    for (int o = 32; o; o >>= 1) { sum += __shfl_down(sum, o); sq += __shfl_down(sq, o); }
    if ((t & 63) == 0) { red[(t >> 6) * 2] = sum; red[(t >> 6) * 2 + 1] = sq; }
    __syncthreads();
    if (t == 0) {
        const float s = red[0] + red[2] + red[4] + red[6];
        const float qq = red[1] + red[3] + red[5] + red[7];
        const float mean = s / (float)M;
        const float var = qq / (float)M - mean * mean;
        mrs[0] = mean; mrs[1] = rsqrtf(var + EPS);
    }
    __syncthreads();
    const float mean = mrs[0], rstd = mrs[1];

    for (int m = t * 4; m < M; m += 1024) {
        const float4 v = *(const float4*)(rowL + m);
        const float4 g = *(const float4*)(gamma_l + m);
        const float4 bt = *(const float4*)(beta_l + m);
        const float o0 = fmaxf(fmaf(g.x * (v.x - mean), rstd, bt.x), 0.f);
        const float o1 = fmaxf(fmaf(g.y * (v.y - mean), rstd, bt.y), 0.f);
        const float o2 = fmaxf(fmaf(g.z * (v.z - mean), rstd, bt.z), 0.f);
        const float o3 = fmaxf(fmaf(g.w * (v.w - mean), rstd, bt.w), 0.f);
        if (WOUT) {
            rowL[m + 0] = o0; rowL[m + 1] = o1; rowL[m + 2] = o2; rowL[m + 3] = o3;
        } else {
            u16 pk[4] = {f2bf(o0), f2bf(o1), f2bf(o2), f2bf(o3)};
            *(uint2*)(actb + (size_t)n * M + m) = *(const uint2*)pk;
        }
    }
    if (WOUT) {   // sparse output layer from the post-LN row in LDS
        __syncthreads();
        pr[t] = w_s[t] * rowL[s_s[t]];
        __syncthreads();
        if (t < 2) {
            float s = 0.f;
            for (int k = 0; k < FAN_IN; ++k) s += pr[t * FAN_IN + k];
            out[(size_t)n * 2 + t] = s + obias[t];
        }
    }
}

// ---------------------------------------------------------------------------
extern "C" void kernel_launch(void* const* d_in, const int* in_sizes, int n_in,
                              void* d_out, int out_size, void* d_ws, size_t ws_size,
                              hipStream_t stream) {
    const float* x        = (const float*)d_in[0];
    const float* weight   = (const float*)d_in[1];
    const float* bias     = (const float*)d_in[2];
    const float* ln_gamma = (const float*)d_in[3];
    const float* ln_beta  = (const float*)d_in[4];
    const int*   edge_src = (const int*)d_in[5];
    float* out = (float*)d_out;

    // ws layout: Cz batch-major [z][512][M], fp16 partials
    f16* Cz1 = (f16*)d_ws;                             // 8 x [512x2048]
    f16* Cz2 = Cz1 + (size_t)8 * 512 * 2048;           // 4 x [512x1024]
    f16* Cz3 = Cz2 + (size_t)4 * 512 * 1024;           // 8 x [512x512]
    u16* xb    = (u16*)(Cz3 + (size_t)8 * 512 * 512);  // [512x4096] bf16
    u16* actb1 = xb + (size_t)512 * 4096;              // [512x2048] bf16
    u16* actb2 = actb1 + (size_t)512 * 2048;           // [512x1024] bf16
    u16* Wd    = actb2 + (size_t)512 * 1024;           // 11534336 bf16

    // 1) prep: densify W1 + x->bf16
    prep<<<2560, 256, 0, stream>>>(weight, edge_src, x, Wd, xb);
    // 2) G1 (512 gemm units, 128x128, Z=8) + densify W2/W3 (1536 units)
    g1d<<<2048, 256, 0, stream>>>(xb, Wd, Cz1, weight, edge_src);
    // 3) fin1 (Z=8) -> actb1
    fin<2048, 8, false><<<512, 256, 0, stream>>>(
        Cz1, bias, ln_gamma, ln_beta, actb1, nullptr, nullptr, nullptr, nullptr);
    // 4) G2: 64x64, Z=4 (512 blocks)
    gemm_bt<<<dim3(16, 8, 4), 256, 0, stream>>>(actb1, Wd + 8388608, Cz2,
                                                1024, 2048, 512);
    // 5) fin2 -> actb2
    fin<1024, 4, false><<<512, 256, 0, stream>>>(
        Cz2, bias + 2048, ln_gamma + 2048, ln_beta + 2048, actb2,
        nullptr, nullptr, nullptr, nullptr);
    // 6) G3: 64x64, Z=8 (512 blocks)
    gemm_bt<<<dim3(8, 8, 8), 256, 0, stream>>>(actb2, Wd + 10485760, Cz3,
                                               512, 1024, 128);
    // 7) fin3 + sparse output layer -> d_out [512, 2]
    fin<512, 8, true><<<512, 256, 0, stream>>>(
        Cz3, bias + 3072, ln_gamma + 3072, ln_beta + 3072, nullptr,
        weight, edge_src, bias + 3584, out);
}